// Round 10
// baseline (237.574 us; speedup 1.0000x reference)
//
#include <hip/hip_runtime.h>

typedef _Float16 hf2 __attribute__((ext_vector_type(2)));

// ---- cross-lane helpers (ds_swizzle BitMode: new_lane = ((lane & and) | or) ^ xor) ----
#define SWZ(v, imm) __int_as_float(__builtin_amdgcn_ds_swizzle(__float_as_int(v), (imm)))
// broadcast lane (group8_base + k) to all 8 lanes of the group: and=0x18 (keep bits 4:3), or=k
#define BCAST(v, k) SWZ(v, (((k) << 5) | 0x18))
#define BCAST8(dst, v)                                                         \
    dst[0] = BCAST(v, 0); dst[1] = BCAST(v, 1); dst[2] = BCAST(v, 2);          \
    dst[3] = BCAST(v, 3); dst[4] = BCAST(v, 4); dst[5] = BCAST(v, 5);          \
    dst[6] = BCAST(v, 6); dst[7] = BCAST(v, 7);
// xor-butterfly within 8-lane group (masks 1,2,4)
#define RXOR(v, m) SWZ(v, (((m) << 10) | 0x1F))

__device__ __forceinline__ float fast_sig(float x) {
    // sigmoid(x) = 1/(1+2^(-x*log2e)) ; exp2 saturates to 0/inf safely
    float e = __builtin_amdgcn_exp2f(-1.44269504088896340736f * x);
    return __builtin_amdgcn_rcpf(1.0f + e);
}
__device__ __forceinline__ float fast_tanh(float x) {
    // tanh(x) = 1 - 2/(2^(2x*log2e)+1) ; +/-inf-safe -> +/-1
    float e = __builtin_amdgcn_exp2f(2.88539008177792681472f * x);
    return 1.0f - 2.0f * __builtin_amdgcn_rcpf(e + 1.0f);
}

constexpr int T_STEPS = 49;

// ROUND-1 PROVEN SCAFFOLD (scalar f32, 8 lanes per batch element, ds_swizzle
// broadcast, NO inline asm in the dot products). ONE change vs round 1:
// the 96 recurrent weights are stored as packed _Float16 pairs (48 VGPRs) and
// each MAC is fmaf((float)w.x, h, acc) -> compiler fuses to v_fma_mix_f32
// (f32 accumulate; weight quantization error ~1e-4 rel, final output ~1e-3
// vs the 2e-2 threshold). The load->cvt->pack chains producing the packed
// weights are NOT single-instruction rematerializable, so the allocator keeps
// them resident instead of re-issuing the ~490 inst/step reload stream that
// capped round 1 at 655 inst/wave-step (measured 1309 cyc/step @ 99.5% VALU).
__global__ __launch_bounds__(256) void lstm2_kernel(
    const float* __restrict__ X,
    const float* __restrict__ W_ih0, const float* __restrict__ W_hh0,
    const float* __restrict__ b_ih0, const float* __restrict__ b_hh0,
    const float* __restrict__ W_ih1, const float* __restrict__ W_hh1,
    const float* __restrict__ b_ih1, const float* __restrict__ b_hh1,
    const float* __restrict__ W_lin, const float* __restrict__ b_lin,
    float* __restrict__ out, int Bn)
{
    const int tid = blockIdx.x * 256 + threadIdx.x;
    const int b   = tid >> 3;            // batch element (8 lanes per element)
    const int j   = threadIdx.x & 7;     // hidden unit owned by this lane

    if (b >= Bn) return;

    // ---- weights: lane j holds rows {j, 8+j, 16+j, 24+j} (i,f,g,o) ----
    float wx0[4], bb0[4], bb1[4];
    hf2 whh0h[4][4], wi1h[4][4], whh1h[4][4];   // f16-packed k-pairs
#pragma unroll
    for (int g = 0; g < 4; ++g) {
        const int r = g * 8 + j;
        wx0[g] = W_ih0[r];
        bb0[g] = b_ih0[r] + b_hh0[r];
        bb1[g] = b_ih1[r] + b_hh1[r];
#pragma unroll
        for (int kp = 0; kp < 4; ++kp) {
            hf2 w0; w0.x = (_Float16)W_hh0[r * 8 + 2 * kp]; w0.y = (_Float16)W_hh0[r * 8 + 2 * kp + 1];
            hf2 w1; w1.x = (_Float16)W_ih1[r * 8 + 2 * kp]; w1.y = (_Float16)W_ih1[r * 8 + 2 * kp + 1];
            hf2 w2; w2.x = (_Float16)W_hh1[r * 8 + 2 * kp]; w2.y = (_Float16)W_hh1[r * 8 + 2 * kp + 1];
            whh0h[g][kp] = w0;
            wi1h[g][kp]  = w1;
            whh1h[g][kp] = w2;
        }
    }
    const float wlin = W_lin[j];
    const float blin = b_lin[0];

    float h1 = 0.f, c1 = 0.f, h2 = 0.f, c2 = 0.f;
    float h1b[8], h2b[8];
#pragma unroll
    for (int k = 0; k < 8; ++k) { h1b[k] = 0.f; h2b[k] = 0.f; }

    const float* xp = X + (long long)b * T_STEPS;

#pragma unroll 1
    for (int t = 0; t < T_STEPS; ++t) {
        const float x = xp[t];

        // ---- layer 1: a = x*W_ih0 + (b_ih0+b_hh0) + W_hh0 @ h1(t-1) ----
        float a[4];
#pragma unroll
        for (int g = 0; g < 4; ++g) {
            a[g] = fmaf(x, wx0[g], bb0[g]);
#pragma unroll
            for (int kp = 0; kp < 4; ++kp) {
                a[g] = fmaf((float)whh0h[g][kp].x, h1b[2 * kp],     a[g]);
                a[g] = fmaf((float)whh0h[g][kp].y, h1b[2 * kp + 1], a[g]);
            }
        }
        float gi = fast_sig(a[0]);
        float gf = fast_sig(a[1]);
        float gg = fast_tanh(a[2]);
        float go = fast_sig(a[3]);
        c1 = fmaf(gf, c1, gi * gg);
        h1 = go * fast_tanh(c1);

        // broadcast new h1 (layer-2 input now, layer-1 recurrent input next step)
        // and old h2 (layer-2 recurrent input)
        BCAST8(h1b, h1);
        BCAST8(h2b, h2);

        // ---- layer 2: a2 = W_ih1 @ h1(t) + (b_ih1+b_hh1) + W_hh1 @ h2(t-1) ----
        float a2[4];
#pragma unroll
        for (int g = 0; g < 4; ++g) {
            a2[g] = bb1[g];
#pragma unroll
            for (int kp = 0; kp < 4; ++kp) {
                a2[g] = fmaf((float)wi1h[g][kp].x, h1b[2 * kp],     a2[g]);
                a2[g] = fmaf((float)wi1h[g][kp].y, h1b[2 * kp + 1], a2[g]);
            }
#pragma unroll
            for (int kp = 0; kp < 4; ++kp) {
                a2[g] = fmaf((float)whh1h[g][kp].x, h2b[2 * kp],     a2[g]);
                a2[g] = fmaf((float)whh1h[g][kp].y, h2b[2 * kp + 1], a2[g]);
            }
        }
        gi = fast_sig(a2[0]);
        gf = fast_sig(a2[1]);
        gg = fast_tanh(a2[2]);
        go = fast_sig(a2[3]);
        c2 = fmaf(gf, c2, gi * gg);
        h2 = go * fast_tanh(c2);
    }

    // ---- epilogue: relu -> linear(H->1) -> relu, lane 0 of each group writes ----
    float v = fmaxf(h2, 0.f) * wlin;
    v += RXOR(v, 1);
    v += RXOR(v, 2);
    v += RXOR(v, 4);
    if (j == 0) out[b] = fmaxf(v + blin, 0.f);
}

extern "C" void kernel_launch(void* const* d_in, const int* in_sizes, int n_in,
                              void* d_out, int out_size, void* d_ws, size_t ws_size,
                              hipStream_t stream) {
    const float* X     = (const float*)d_in[0];
    const float* W_ih0 = (const float*)d_in[1];
    const float* W_hh0 = (const float*)d_in[2];
    const float* b_ih0 = (const float*)d_in[3];
    const float* b_hh0 = (const float*)d_in[4];
    const float* W_ih1 = (const float*)d_in[5];
    const float* W_hh1 = (const float*)d_in[6];
    const float* b_ih1 = (const float*)d_in[7];
    const float* b_hh1 = (const float*)d_in[8];
    const float* W_lin = (const float*)d_in[9];
    const float* b_lin = (const float*)d_in[10];
    float* out = (float*)d_out;

    const int Bn = in_sizes[0] / T_STEPS;       // 131072
    const int threads = Bn * 8;                 // 8 lanes per batch element
    const int block = 256;
    const int grid = (threads + block - 1) / block;

    lstm2_kernel<<<grid, block, 0, stream>>>(X, W_ih0, W_hh0, b_ih0, b_hh0,
                                             W_ih1, W_hh1, b_ih1, b_hh1,
                                             W_lin, b_lin, out, Bn);
}